// Round 9
// baseline (214.372 us; speedup 1.0000x reference)
//
#include <hip/hip_runtime.h>

// GIN 2-layer forward — CSR counting sort + bf16 gather tables + reg-tiled GEMMs.
// Pipeline:
//   cvt_bf16: xh = bf16(node_emb)
//   bin_hist -> scan_bins -> partition -> bin_finalize   (CSR by dst)
//   agg1 = x + gather_bf16(xh)         [gather64h, 8-deep]
//   h    = relu(agg1 @ W1 + b1)        [gemm1_relu, 4x16 reg tile, h packed bf16]
//   gemm2: g = h @ W2 ; gh = bf16(g) ; out = g + b2      [4x8 reg tile]
//   out += gather_bf16(gh)             [gather64h]
// (W2 folded before aggregation-2: (A h + h) W2 + b2 = A(hW2) + hW2 + b2.)
// R5: don't fuse gather into GEMM (occupancy). R6: gather is cache-BW bound ->
// bf16 tables. R7: 4 FMA / 2 LDS-read ratio was LDS-bound. R8: 16 FMA / 5 LDS
// still LDS-bound at 38% VALU -> this round: 32-64 FMA per 5-8 LDS reads,
// conflict-free odd strides, K-phased staging.

#define EPB 4096
#define CAP 6144

__device__ __forceinline__ unsigned short f2b(float f) {   // RNE f32->bf16
    unsigned u = __float_as_uint(f);
    return (unsigned short)((u + 0x7fffu + ((u >> 16) & 1u)) >> 16);
}
__device__ __forceinline__ unsigned pk(float a, float b) {
    return (unsigned)f2b(a) | ((unsigned)f2b(b) << 16);
}
__device__ __forceinline__ float bl(unsigned u) { return __uint_as_float(u << 16); }
__device__ __forceinline__ float bh(unsigned u) { return __uint_as_float(u & 0xffff0000u); }

__global__ void cvt_bf16(const float4* __restrict__ x4, uint2* __restrict__ xh, int n16) {
    int i = blockIdx.x * blockDim.x + threadIdx.x;
    if (i >= n16) return;
    float4 v = x4[i];
    xh[i] = make_uint2(pk(v.x, v.y), pk(v.z, v.w));
}

__global__ __launch_bounds__(256) void bin_hist(const int* __restrict__ dst,
                                                int* __restrict__ binCnt, int ne, int nbins) {
    __shared__ int h[512];
    int t = threadIdx.x;
    for (int i = t; i < nbins; i += 256) h[i] = 0;
    __syncthreads();
    int eb = blockIdx.x * EPB;
#pragma unroll
    for (int i = 0; i < 16; ++i) {
        int e = eb + t + i * 256;
        if (e < ne) atomicAdd(&h[dst[e] >> 8], 1);
    }
    __syncthreads();
    for (int i = t; i < nbins; i += 256) if (h[i]) atomicAdd(&binCnt[i], h[i]);
}

__global__ __launch_bounds__(512) void scan_bins(const int* __restrict__ binCnt,
                                                 int* __restrict__ binOff, int* __restrict__ binCur,
                                                 int* __restrict__ off, int nbins, int n, int ne) {
    __shared__ int s[512];
    int t = threadIdx.x;
    int v = (t < nbins) ? binCnt[t] : 0;
    s[t] = v;
    __syncthreads();
    for (int o = 1; o < 512; o <<= 1) {
        int u = (t >= o) ? s[t - o] : 0;
        __syncthreads();
        s[t] += u;
        __syncthreads();
    }
    if (t < nbins) { int b = s[t] - v; binOff[t] = b; binCur[t] = b; }
    if (t == 0) { binOff[nbins] = ne; off[n] = ne; }
}

__global__ __launch_bounds__(256) void partition(const int* __restrict__ src,
                                                 const int* __restrict__ dst,
                                                 int* __restrict__ binCur,
                                                 unsigned* __restrict__ part, int ne, int nbins) {
    __shared__ int h[512];
    __shared__ int base[512];
    int t = threadIdx.x;
    for (int i = t; i < nbins; i += 256) h[i] = 0;
    __syncthreads();
    int eb = blockIdx.x * EPB;
    int ss[16], ds[16];
#pragma unroll
    for (int i = 0; i < 16; ++i) {
        int e = eb + t + i * 256;
        if (e < ne) { ss[i] = src[e]; ds[i] = dst[e]; atomicAdd(&h[ds[i] >> 8], 1); }
        else ds[i] = -1;
    }
    __syncthreads();
    for (int i = t; i < nbins; i += 256) base[i] = h[i] ? atomicAdd(&binCur[i], h[i]) : 0;
    __syncthreads();
    for (int i = t; i < nbins; i += 256) h[i] = 0;
    __syncthreads();
#pragma unroll
    for (int i = 0; i < 16; ++i) {
        if (ds[i] >= 0) {
            int b = ds[i] >> 8;
            int p = atomicAdd(&h[b], 1);
            part[base[b] + p] = ((unsigned)ss[i] << 8) | (unsigned)(ds[i] & 255);
        }
    }
}

__global__ __launch_bounds__(256) void bin_finalize(const unsigned* __restrict__ part,
                                                    const int* __restrict__ binOff,
                                                    int* __restrict__ off, int* __restrict__ perm,
                                                    int n, int nbins) {
    __shared__ unsigned st[CAP];
    __shared__ int cnt[256], ex[256], cur[256];
    int b = blockIdx.x;
    int t = threadIdx.x;
    int e0 = binOff[b], e1 = binOff[b + 1];
    int m = e1 - e0;
    int nb0 = b << 8;
    int nn = min(256, n - nb0);
    cnt[t] = 0;
    __syncthreads();
    bool staged = (m <= CAP);
    if (staged) {
        for (int i = t; i < m; i += 256) { unsigned v = part[e0 + i]; st[i] = v; atomicAdd(&cnt[v & 255u], 1); }
    } else {
        for (int i = t; i < m; i += 256) { unsigned v = part[e0 + i]; atomicAdd(&cnt[v & 255u], 1); }
    }
    __syncthreads();
    int v = cnt[t];
    ex[t] = v;
    __syncthreads();
    for (int o = 1; o < 256; o <<= 1) {
        int u = (t >= o) ? ex[t - o] : 0;
        __syncthreads();
        ex[t] += u;
        __syncthreads();
    }
    int excl = ex[t] - v;
    if (t < nn) off[nb0 + t] = e0 + excl;
    cur[t] = excl;
    __syncthreads();
    if (staged) {
        for (int i = t; i < m; i += 256) {
            unsigned w = st[i];
            int p = atomicAdd(&cur[w & 255u], 1);
            perm[e0 + p] = (int)(w >> 8);
        }
    } else {
        for (int i = t; i < m; i += 256) {
            unsigned w = part[e0 + i];
            int p = atomicAdd(&cur[w & 255u], 1);
            perm[e0 + p] = (int)(w >> 8);
        }
    }
}

// out[i] = selfSrc[i] + sum_{e in CSR(i)} bf16_table[perm[e]]  (8-deep batch)
__global__ __launch_bounds__(256) void gather64h(const uint2* __restrict__ xh,
                                                 const float4* selfSrc,
                                                 const int* __restrict__ off,
                                                 const int* __restrict__ perm,
                                                 float4* out4, int n) {
    int t = threadIdx.x;
    int node = blockIdx.x * 16 + (t >> 4);
    int c = t & 15;
    if (node >= n) return;
    int beg = off[node], end = off[node + 1];
    float4 acc = selfSrc[(size_t)node * 16 + c];
    int e = beg;
    for (; e + 8 <= end; e += 8) {
        int s0 = perm[e],     s1 = perm[e + 1], s2 = perm[e + 2], s3 = perm[e + 3];
        int s4 = perm[e + 4], s5 = perm[e + 5], s6 = perm[e + 6], s7 = perm[e + 7];
        uint2 v0 = xh[(size_t)s0 * 16 + c];
        uint2 v1 = xh[(size_t)s1 * 16 + c];
        uint2 v2 = xh[(size_t)s2 * 16 + c];
        uint2 v3 = xh[(size_t)s3 * 16 + c];
        uint2 v4 = xh[(size_t)s4 * 16 + c];
        uint2 v5 = xh[(size_t)s5 * 16 + c];
        uint2 v6 = xh[(size_t)s6 * 16 + c];
        uint2 v7 = xh[(size_t)s7 * 16 + c];
        acc.x += ((bl(v0.x) + bl(v1.x)) + (bl(v2.x) + bl(v3.x))) +
                 ((bl(v4.x) + bl(v5.x)) + (bl(v6.x) + bl(v7.x)));
        acc.y += ((bh(v0.x) + bh(v1.x)) + (bh(v2.x) + bh(v3.x))) +
                 ((bh(v4.x) + bh(v5.x)) + (bh(v6.x) + bh(v7.x)));
        acc.z += ((bl(v0.y) + bl(v1.y)) + (bl(v2.y) + bl(v3.y))) +
                 ((bl(v4.y) + bl(v5.y)) + (bl(v6.y) + bl(v7.y)));
        acc.w += ((bh(v0.y) + bh(v1.y)) + (bh(v2.y) + bh(v3.y))) +
                 ((bh(v4.y) + bh(v5.y)) + (bh(v6.y) + bh(v7.y)));
    }
    for (; e + 4 <= end; e += 4) {
        int s0 = perm[e], s1 = perm[e + 1], s2 = perm[e + 2], s3 = perm[e + 3];
        uint2 v0 = xh[(size_t)s0 * 16 + c];
        uint2 v1 = xh[(size_t)s1 * 16 + c];
        uint2 v2 = xh[(size_t)s2 * 16 + c];
        uint2 v3 = xh[(size_t)s3 * 16 + c];
        acc.x += (bl(v0.x) + bl(v1.x)) + (bl(v2.x) + bl(v3.x));
        acc.y += (bh(v0.x) + bh(v1.x)) + (bh(v2.x) + bh(v3.x));
        acc.z += (bl(v0.y) + bl(v1.y)) + (bl(v2.y) + bl(v3.y));
        acc.w += (bh(v0.y) + bh(v1.y)) + (bh(v2.y) + bh(v3.y));
    }
    for (; e < end; ++e) {
        int s = perm[e];
        uint2 v = xh[(size_t)s * 16 + c];
        acc.x += bl(v.x); acc.y += bh(v.x); acc.z += bl(v.y); acc.w += bh(v.y);
    }
    out4[(size_t)node * 16 + c] = acc;
}

// h[n,128] = relu(x[n,64] @ W1 + b1), h packed bf16.
// 128 rows/block; thread (rg=t>>3, cg=t&7): rows 4rg..+3, f4 cols {cg,+8,+16,+24}.
// Per k: 4 broadcast b32 + 4 b128 (all-bank) feed 64 FMAs -> VALU-bound.
__global__ __launch_bounds__(256) void gemm1_relu(const float* __restrict__ x,
                                                  const float* __restrict__ W1,
                                                  const float* __restrict__ b1,
                                                  uint2* __restrict__ h, int n) {
    __shared__ float4 Ws[64][32];   // 32 KiB
    __shared__ float  xs[128][33];  // 16.9 KiB; stride 33 -> rows spaced 4 hit 8 banks
    int t = threadIdx.x;
    const float4* W4 = reinterpret_cast<const float4*>(W1);
    for (int i = t; i < 64 * 32; i += 256) Ws[i >> 5][i & 31] = W4[i];
    int row0 = blockIdx.x * 128;
    int rg = t >> 3, cg = t & 7;
    float4 acc[4][4];
#pragma unroll
    for (int r = 0; r < 4; ++r)
#pragma unroll
        for (int j = 0; j < 4; ++j) acc[r][j] = make_float4(0.f, 0.f, 0.f, 0.f);

    for (int kt = 0; kt < 2; ++kt) {
        __syncthreads();                         // also covers Ws on first iter
        for (int i = t; i < 1024; i += 256) {    // 128 rows x 8 f4 (K-phase of 32)
            int r = i >> 3, c = i & 7;
            if (row0 + r < n) {
                float4 v = reinterpret_cast<const float4*>(x)[(size_t)(row0 + r) * 16 + kt * 8 + c];
                xs[r][c * 4 + 0] = v.x; xs[r][c * 4 + 1] = v.y;
                xs[r][c * 4 + 2] = v.z; xs[r][c * 4 + 3] = v.w;
            }
        }
        __syncthreads();
#pragma unroll 2
        for (int kk = 0; kk < 32; ++kk) {
            int k = kt * 32 + kk;
            float4 w0 = Ws[k][cg], w1 = Ws[k][cg + 8], w2 = Ws[k][cg + 16], w3 = Ws[k][cg + 24];
#pragma unroll
            for (int r = 0; r < 4; ++r) {
                float a = xs[4 * rg + r][kk];
                acc[r][0].x += a * w0.x; acc[r][0].y += a * w0.y; acc[r][0].z += a * w0.z; acc[r][0].w += a * w0.w;
                acc[r][1].x += a * w1.x; acc[r][1].y += a * w1.y; acc[r][1].z += a * w1.z; acc[r][1].w += a * w1.w;
                acc[r][2].x += a * w2.x; acc[r][2].y += a * w2.y; acc[r][2].z += a * w2.z; acc[r][2].w += a * w2.w;
                acc[r][3].x += a * w3.x; acc[r][3].y += a * w3.y; acc[r][3].z += a * w3.z; acc[r][3].w += a * w3.w;
            }
        }
    }
    const float4* b4 = reinterpret_cast<const float4*>(b1);
    float4 q[4] = { b4[cg], b4[cg + 8], b4[cg + 16], b4[cg + 24] };
#pragma unroll
    for (int r = 0; r < 4; ++r) {
        int row = row0 + 4 * rg + r;
        if (row >= n) break;
        size_t base = (size_t)row * 32;
#pragma unroll
        for (int j = 0; j < 4; ++j) {
            float4 m;
            m.x = fmaxf(acc[r][j].x + q[j].x, 0.f);
            m.y = fmaxf(acc[r][j].y + q[j].y, 0.f);
            m.z = fmaxf(acc[r][j].z + q[j].z, 0.f);
            m.w = fmaxf(acc[r][j].w + q[j].w, 0.f);
            h[base + cg + 8 * j] = make_uint2(pk(m.x, m.y), pk(m.z, m.w));
        }
    }
}

// g = h[n,128(bf16)] @ W2[128,64]; gh = bf16(g); out = g + b2 (f32).
// 128 rows/block; thread (rg=t>>3, cg=t&7): rows 4rg..+3, f4 cols {cg, cg+8}.
// Per k: 4 broadcast b32 + 2 b128 feed 32 FMAs -> VALU-bound. K in 4 phases.
__global__ __launch_bounds__(256) void gemm2(const unsigned* __restrict__ h,
                                             const float* __restrict__ W2,
                                             const float* __restrict__ b2,
                                             uint2* __restrict__ gh,
                                             float4* __restrict__ out4, int n) {
    __shared__ float4 Ws[128][16];  // 32 KiB
    __shared__ float  hs[128][33];  // 16.9 KiB
    int t = threadIdx.x;
    const float4* W4 = reinterpret_cast<const float4*>(W2);
    for (int i = t; i < 128 * 16; i += 256) Ws[i >> 4][i & 15] = W4[i];
    int row0 = blockIdx.x * 128;
    int rg = t >> 3, cg = t & 7;
    float4 acc[4][2];
#pragma unroll
    for (int r = 0; r < 4; ++r) { acc[r][0] = make_float4(0.f,0.f,0.f,0.f); acc[r][1] = make_float4(0.f,0.f,0.f,0.f); }

    for (int kt = 0; kt < 4; ++kt) {
        __syncthreads();
        for (int i = t; i < 2048; i += 256) {    // 128 rows x 16 u32 (=32 bf16)
            int r = i >> 4, c = i & 15;
            if (row0 + r < n) {
                unsigned u = h[(size_t)(row0 + r) * 64 + kt * 16 + c];
                hs[r][c * 2]     = bl(u);
                hs[r][c * 2 + 1] = bh(u);
            }
        }
        __syncthreads();
#pragma unroll 4
        for (int kk = 0; kk < 32; ++kk) {
            int k = kt * 32 + kk;
            float4 w0 = Ws[k][cg], w1 = Ws[k][cg + 8];
#pragma unroll
            for (int r = 0; r < 4; ++r) {
                float a = hs[4 * rg + r][kk];
                acc[r][0].x += a * w0.x; acc[r][0].y += a * w0.y; acc[r][0].z += a * w0.z; acc[r][0].w += a * w0.w;
                acc[r][1].x += a * w1.x; acc[r][1].y += a * w1.y; acc[r][1].z += a * w1.z; acc[r][1].w += a * w1.w;
            }
        }
    }
    const float4* b4 = reinterpret_cast<const float4*>(b2);
    float4 q0 = b4[cg], q1 = b4[cg + 8];
#pragma unroll
    for (int r = 0; r < 4; ++r) {
        int row = row0 + 4 * rg + r;
        if (row >= n) break;
        size_t o = (size_t)row * 16;
        gh[o + cg]     = make_uint2(pk(acc[r][0].x, acc[r][0].y), pk(acc[r][0].z, acc[r][0].w));
        gh[o + cg + 8] = make_uint2(pk(acc[r][1].x, acc[r][1].y), pk(acc[r][1].z, acc[r][1].w));
        out4[o + cg]     = make_float4(acc[r][0].x + q0.x, acc[r][0].y + q0.y,
                                       acc[r][0].z + q0.z, acc[r][0].w + q0.w);
        out4[o + cg + 8] = make_float4(acc[r][1].x + q1.x, acc[r][1].y + q1.y,
                                       acc[r][1].z + q1.z, acc[r][1].w + q1.w);
    }
}

extern "C" void kernel_launch(void* const* d_in, const int* in_sizes, int n_in,
                              void* d_out, int out_size, void* d_ws, size_t ws_size,
                              hipStream_t stream) {
    const float* node_emb = (const float*)d_in[0];
    const float* W1 = (const float*)d_in[1];
    const float* b1 = (const float*)d_in[2];
    const float* W2 = (const float*)d_in[3];
    const float* b2 = (const float*)d_in[4];
    const int*   ei = (const int*)d_in[5];
    int n  = in_sizes[0] / 64;
    int ne = in_sizes[5] / 2;
    const int* src = ei;
    const int* dst = ei + ne;
    float* out = (float*)d_out;

    int nbins = (n + 255) >> 8;   // 391

    // workspace layout:
    //   agg1 [n*64 f32, 25.6MB]    ; gh aliases agg1 (agg1 dead after gemm1)
    //   hslot [51.2MB]: h (bf16, 25.6MB) written by gemm1.
    //     part aliases hslot[0..6.4MB], xh aliases hslot[8MB..20.8MB] —
    //     both dead before gemm1 writes h.
    char* ws = (char*)d_ws;
    float* agg1 = (float*)ws;
    char*  hslot = ws + (size_t)n * 64 * 4;
    uint2* h    = (uint2*)hslot;
    unsigned* part = (unsigned*)hslot;
    uint2* xh   = (uint2*)(hslot + (size_t)8 * 1024 * 1024);
    uint2* gh   = (uint2*)agg1;
    char*  p    = ws + (size_t)n * 64 * 4 + (size_t)n * 128 * 4;
    int* off    = (int*)p;            p += (size_t)(n + 1) * 4;
    int* perm   = (int*)p;            p += (size_t)ne * 4;
    int* binCnt = (int*)p;            p += (size_t)(nbins + 1) * 4;
    int* binOff = (int*)p;            p += (size_t)(nbins + 1) * 4;
    int* binCur = (int*)p;            p += (size_t)(nbins + 1) * 4;

    int nblk = (ne + EPB - 1) / EPB;

    cvt_bf16<<<(n * 16 + 255) / 256, 256, 0, stream>>>((const float4*)node_emb, xh, n * 16);
    hipMemsetAsync(binCnt, 0, (size_t)nbins * 4, stream);
    bin_hist<<<nblk, 256, 0, stream>>>(dst, binCnt, ne, nbins);
    scan_bins<<<1, 512, 0, stream>>>(binCnt, binOff, binCur, off, nbins, n, ne);
    partition<<<nblk, 256, 0, stream>>>(src, dst, binCur, part, ne, nbins);
    bin_finalize<<<nbins, 256, 0, stream>>>(part, binOff, off, perm, n, nbins);

    gather64h<<<(n + 15) / 16, 256, 0, stream>>>(xh, (const float4*)node_emb, off, perm,
                                                 (float4*)agg1, n);
    gemm1_relu<<<(n + 127) / 128, 256, 0, stream>>>(agg1, W1, b1, h, n);
    gemm2<<<(n + 127) / 128, 256, 0, stream>>>((const unsigned*)h, W2, b2, gh, (float4*)out, n);
    gather64h<<<(n + 15) / 16, 256, 0, stream>>>(gh, (const float4*)out, off, perm,
                                                 (float4*)out, n);
}

// Round 10
// 160.636 us; speedup vs baseline: 1.3345x; 1.3345x over previous
//
#include <hip/hip_runtime.h>

// GIN 2-layer forward — CSR counting sort + bf16 gather tables + fused MFMA MLP.
// Pipeline:
//   cvt_bf16: xh = bf16(node_emb); prep W1t/W2t (bf16, transposed for B-frags)
//   bin_hist -> scan_bins -> partition -> bin_finalize   (CSR by dst)
//   agg1h = bf16(x + gather_bf16(xh))    [gather64h_b16, 8-deep]
//   mlp_fused: h = relu(agg1h@W1+b1) (LDS only, bf16)
//              g = h@W2 ; out = g + b2 (f32) ; gh = bf16(g)   [MFMA 16x16x32]
//   out += gather_bf16(gh)               [gather64h]
// (W2 folded before aggregation-2: (A h + h) W2 + b2 = A(hW2) + hW2 + b2.)
// R5: don't fuse gather into GEMM (occupancy). R6: gather cache-BW bound ->
// bf16 tables. R7/R8/R9: f32 vector GEMM stuck at 31-39% VALU (LDS-rate /
// barrier-latency trap) -> MFMA + full-MLP fusion, h stays in LDS.

#define EPB 4096
#define CAP 6144
#define LDST 136   // LDS h row stride in u16 (272 B, 16B-aligned)

typedef __attribute__((ext_vector_type(8))) short bf16x8;
typedef __attribute__((ext_vector_type(4))) float f32x4;

__device__ __forceinline__ unsigned short f2b(float f) {   // RNE f32->bf16
    unsigned u = __float_as_uint(f);
    return (unsigned short)((u + 0x7fffu + ((u >> 16) & 1u)) >> 16);
}
__device__ __forceinline__ unsigned pk(float a, float b) {
    return (unsigned)f2b(a) | ((unsigned)f2b(b) << 16);
}
__device__ __forceinline__ float bl(unsigned u) { return __uint_as_float(u << 16); }
__device__ __forceinline__ float bh(unsigned u) { return __uint_as_float(u & 0xffff0000u); }

__global__ void cvt_bf16(const float4* __restrict__ x4, uint2* __restrict__ xh, int n16) {
    int i = blockIdx.x * blockDim.x + threadIdx.x;
    if (i >= n16) return;
    float4 v = x4[i];
    xh[i] = make_uint2(pk(v.x, v.y), pk(v.z, v.w));
}

// W1 [64][128] f32 -> W1t [128 cols][64 k] bf16
__global__ void prep_w1t(const float* __restrict__ W1, unsigned short* __restrict__ w1t) {
    int i = blockIdx.x * 256 + threadIdx.x;
    if (i >= 128 * 64) return;
    int c = i >> 6, k = i & 63;
    w1t[i] = f2b(W1[k * 128 + c]);
}
// W2 [128][64] f32 -> W2t [64 cols][128 k] bf16
__global__ void prep_w2t(const float* __restrict__ W2, unsigned short* __restrict__ w2t) {
    int i = blockIdx.x * 256 + threadIdx.x;
    if (i >= 64 * 128) return;
    int c = i >> 7, k = i & 127;
    w2t[i] = f2b(W2[k * 64 + c]);
}

__global__ __launch_bounds__(256) void bin_hist(const int* __restrict__ dst,
                                                int* __restrict__ binCnt, int ne, int nbins) {
    __shared__ int h[512];
    int t = threadIdx.x;
    for (int i = t; i < nbins; i += 256) h[i] = 0;
    __syncthreads();
    int eb = blockIdx.x * EPB;
#pragma unroll
    for (int i = 0; i < 16; ++i) {
        int e = eb + t + i * 256;
        if (e < ne) atomicAdd(&h[dst[e] >> 8], 1);
    }
    __syncthreads();
    for (int i = t; i < nbins; i += 256) if (h[i]) atomicAdd(&binCnt[i], h[i]);
}

__global__ __launch_bounds__(512) void scan_bins(const int* __restrict__ binCnt,
                                                 int* __restrict__ binOff, int* __restrict__ binCur,
                                                 int* __restrict__ off, int nbins, int n, int ne) {
    __shared__ int s[512];
    int t = threadIdx.x;
    int v = (t < nbins) ? binCnt[t] : 0;
    s[t] = v;
    __syncthreads();
    for (int o = 1; o < 512; o <<= 1) {
        int u = (t >= o) ? s[t - o] : 0;
        __syncthreads();
        s[t] += u;
        __syncthreads();
    }
    if (t < nbins) { int b = s[t] - v; binOff[t] = b; binCur[t] = b; }
    if (t == 0) { binOff[nbins] = ne; off[n] = ne; }
}

__global__ __launch_bounds__(256) void partition(const int* __restrict__ src,
                                                 const int* __restrict__ dst,
                                                 int* __restrict__ binCur,
                                                 unsigned* __restrict__ part, int ne, int nbins) {
    __shared__ int h[512];
    __shared__ int base[512];
    int t = threadIdx.x;
    for (int i = t; i < nbins; i += 256) h[i] = 0;
    __syncthreads();
    int eb = blockIdx.x * EPB;
    int ss[16], ds[16];
#pragma unroll
    for (int i = 0; i < 16; ++i) {
        int e = eb + t + i * 256;
        if (e < ne) { ss[i] = src[e]; ds[i] = dst[e]; atomicAdd(&h[ds[i] >> 8], 1); }
        else ds[i] = -1;
    }
    __syncthreads();
    for (int i = t; i < nbins; i += 256) base[i] = h[i] ? atomicAdd(&binCur[i], h[i]) : 0;
    __syncthreads();
    for (int i = t; i < nbins; i += 256) h[i] = 0;
    __syncthreads();
#pragma unroll
    for (int i = 0; i < 16; ++i) {
        if (ds[i] >= 0) {
            int b = ds[i] >> 8;
            int p = atomicAdd(&h[b], 1);
            part[base[b] + p] = ((unsigned)ss[i] << 8) | (unsigned)(ds[i] & 255);
        }
    }
}

__global__ __launch_bounds__(256) void bin_finalize(const unsigned* __restrict__ part,
                                                    const int* __restrict__ binOff,
                                                    int* __restrict__ off, int* __restrict__ perm,
                                                    int n, int nbins) {
    __shared__ unsigned st[CAP];
    __shared__ int cnt[256], ex[256], cur[256];
    int b = blockIdx.x;
    int t = threadIdx.x;
    int e0 = binOff[b], e1 = binOff[b + 1];
    int m = e1 - e0;
    int nb0 = b << 8;
    int nn = min(256, n - nb0);
    cnt[t] = 0;
    __syncthreads();
    bool staged = (m <= CAP);
    if (staged) {
        for (int i = t; i < m; i += 256) { unsigned v = part[e0 + i]; st[i] = v; atomicAdd(&cnt[v & 255u], 1); }
    } else {
        for (int i = t; i < m; i += 256) { unsigned v = part[e0 + i]; atomicAdd(&cnt[v & 255u], 1); }
    }
    __syncthreads();
    int v = cnt[t];
    ex[t] = v;
    __syncthreads();
    for (int o = 1; o < 256; o <<= 1) {
        int u = (t >= o) ? ex[t - o] : 0;
        __syncthreads();
        ex[t] += u;
        __syncthreads();
    }
    int excl = ex[t] - v;
    if (t < nn) off[nb0 + t] = e0 + excl;
    cur[t] = excl;
    __syncthreads();
    if (staged) {
        for (int i = t; i < m; i += 256) {
            unsigned w = st[i];
            int p = atomicAdd(&cur[w & 255u], 1);
            perm[e0 + p] = (int)(w >> 8);
        }
    } else {
        for (int i = t; i < m; i += 256) {
            unsigned w = part[e0 + i];
            int p = atomicAdd(&cur[w & 255u], 1);
            perm[e0 + p] = (int)(w >> 8);
        }
    }
}

// acc = selfSrc[i] + sum bf16_table[perm[e]]  (8-deep). Two output flavors.
#define GATHER_BODY                                                              \
    int t = threadIdx.x;                                                         \
    int node = blockIdx.x * 16 + (t >> 4);                                       \
    int c = t & 15;                                                              \
    if (node >= n) return;                                                       \
    int beg = off[node], end = off[node + 1];                                    \
    float4 acc = selfSrc[(size_t)node * 16 + c];                                 \
    int e = beg;                                                                 \
    for (; e + 8 <= end; e += 8) {                                               \
        int s0 = perm[e],     s1 = perm[e + 1], s2 = perm[e + 2], s3 = perm[e + 3]; \
        int s4 = perm[e + 4], s5 = perm[e + 5], s6 = perm[e + 6], s7 = perm[e + 7]; \
        uint2 v0 = xh[(size_t)s0 * 16 + c];                                      \
        uint2 v1 = xh[(size_t)s1 * 16 + c];                                      \
        uint2 v2 = xh[(size_t)s2 * 16 + c];                                      \
        uint2 v3 = xh[(size_t)s3 * 16 + c];                                      \
        uint2 v4 = xh[(size_t)s4 * 16 + c];                                      \
        uint2 v5 = xh[(size_t)s5 * 16 + c];                                      \
        uint2 v6 = xh[(size_t)s6 * 16 + c];                                      \
        uint2 v7 = xh[(size_t)s7 * 16 + c];                                      \
        acc.x += ((bl(v0.x) + bl(v1.x)) + (bl(v2.x) + bl(v3.x))) +               \
                 ((bl(v4.x) + bl(v5.x)) + (bl(v6.x) + bl(v7.x)));                \
        acc.y += ((bh(v0.x) + bh(v1.x)) + (bh(v2.x) + bh(v3.x))) +               \
                 ((bh(v4.x) + bh(v5.x)) + (bh(v6.x) + bh(v7.x)));                \
        acc.z += ((bl(v0.y) + bl(v1.y)) + (bl(v2.y) + bl(v3.y))) +               \
                 ((bl(v4.y) + bl(v5.y)) + (bl(v6.y) + bl(v7.y)));                \
        acc.w += ((bh(v0.y) + bh(v1.y)) + (bh(v2.y) + bh(v3.y))) +               \
                 ((bh(v4.y) + bh(v5.y)) + (bh(v6.y) + bh(v7.y)));                \
    }                                                                            \
    for (; e + 4 <= end; e += 4) {                                               \
        int s0 = perm[e], s1 = perm[e + 1], s2 = perm[e + 2], s3 = perm[e + 3];  \
        uint2 v0 = xh[(size_t)s0 * 16 + c];                                      \
        uint2 v1 = xh[(size_t)s1 * 16 + c];                                      \
        uint2 v2 = xh[(size_t)s2 * 16 + c];                                      \
        uint2 v3 = xh[(size_t)s3 * 16 + c];                                      \
        acc.x += (bl(v0.x) + bl(v1.x)) + (bl(v2.x) + bl(v3.x));                  \
        acc.y += (bh(v0.x) + bh(v1.x)) + (bh(v2.x) + bh(v3.x));                  \
        acc.z += (bl(v0.y) + bl(v1.y)) + (bl(v2.y) + bl(v3.y));                  \
        acc.w += (bh(v0.y) + bh(v1.y)) + (bh(v2.y) + bh(v3.y));                  \
    }                                                                            \
    for (; e < end; ++e) {                                                       \
        int s = perm[e];                                                         \
        uint2 v = xh[(size_t)s * 16 + c];                                        \
        acc.x += bl(v.x); acc.y += bh(v.x); acc.z += bl(v.y); acc.w += bh(v.y);  \
    }

__global__ __launch_bounds__(256) void gather64h(const uint2* __restrict__ xh,
                                                 const float4* selfSrc,
                                                 const int* __restrict__ off,
                                                 const int* __restrict__ perm,
                                                 float4* out4, int n) {
    GATHER_BODY
    out4[(size_t)node * 16 + c] = acc;
}

__global__ __launch_bounds__(256) void gather64h_b16(const uint2* __restrict__ xh,
                                                     const float4* __restrict__ selfSrc,
                                                     const int* __restrict__ off,
                                                     const int* __restrict__ perm,
                                                     uint2* __restrict__ outh, int n) {
    GATHER_BODY
    outh[(size_t)node * 16 + c] = make_uint2(pk(acc.x, acc.y), pk(acc.z, acc.w));
}

// Fused MLP via MFMA 16x16x32 bf16. Block = 256 thr = 4 waves, 128 rows/block
// (32 rows/wave). Phase 1: h=relu(A@W1+b1) -> LDS bf16 (each wave writes only
// its own 32 rows -> no __syncthreads anywhere). Phase 2: g=h@W2 from LDS;
// out = g+b2 (f32), gh = bf16(g).
// Fragment layouts (guide m89-verified): A: row=l&15, k=(l>>4)*8+j;
// B: col=l&15, k=(l>>4)*8+j (W stored transposed [col][k]);
// D: col=l&15, row=(l>>4)*4+reg.
__global__ __launch_bounds__(256) void mlp_fused(const unsigned short* __restrict__ ah,
                                                 const unsigned short* __restrict__ w1t,
                                                 const float* __restrict__ b1,
                                                 const unsigned short* __restrict__ w2t,
                                                 const float* __restrict__ b2,
                                                 unsigned short* __restrict__ gh,
                                                 float* __restrict__ out, int n) {
    __shared__ unsigned short hl[128][LDST];   // 34.8 KiB
    int t = threadIdx.x;
    int w = t >> 6;
    int l = t & 63;
    int lr = l & 15;
    int lg = l >> 4;
    int row0 = blockIdx.x * 128 + w * 32;

    // ---- phase 1: h = relu(agg1h @ W1 + b1) -> LDS ----
    bf16x8 b1f[8][2];
#pragma unroll
    for (int ct = 0; ct < 8; ++ct)
#pragma unroll
        for (int kc = 0; kc < 2; ++kc)
            b1f[ct][kc] = *reinterpret_cast<const bf16x8*>(
                w1t + (size_t)(ct * 16 + lr) * 64 + kc * 32 + lg * 8);
    float bias1[8];
#pragma unroll
    for (int ct = 0; ct < 8; ++ct) bias1[ct] = b1[ct * 16 + lr];

#pragma unroll
    for (int rt = 0; rt < 2; ++rt) {
        int arow = row0 + rt * 16 + lr;
        if (arow > n - 1) arow = n - 1;
        bf16x8 a0 = *reinterpret_cast<const bf16x8*>(ah + (size_t)arow * 64 + lg * 8);
        bf16x8 a1 = *reinterpret_cast<const bf16x8*>(ah + (size_t)arow * 64 + 32 + lg * 8);
        int lrow = w * 32 + rt * 16 + lg * 4;
#pragma unroll
        for (int ct = 0; ct < 8; ++ct) {
            f32x4 acc = {0.f, 0.f, 0.f, 0.f};
            acc = __builtin_amdgcn_mfma_f32_16x16x32_bf16(a0, b1f[ct][0], acc, 0, 0, 0);
            acc = __builtin_amdgcn_mfma_f32_16x16x32_bf16(a1, b1f[ct][1], acc, 0, 0, 0);
#pragma unroll
            for (int r = 0; r < 4; ++r) {
                float v = fmaxf(acc[r] + bias1[ct], 0.f);
                hl[lrow + r][ct * 16 + lr] = f2b(v);
            }
        }
    }

    // ---- phase 2: g = h @ W2 (same-wave LDS reuse; compiler inserts waits) ----
    bf16x8 b2f[4][4];
#pragma unroll
    for (int ct = 0; ct < 4; ++ct)
#pragma unroll
        for (int kc = 0; kc < 4; ++kc)
            b2f[ct][kc] = *reinterpret_cast<const bf16x8*>(
                w2t + (size_t)(ct * 16 + lr) * 128 + kc * 32 + lg * 8);
    float bias2[4];
#pragma unroll
    for (int ct = 0; ct < 4; ++ct) bias2[ct] = b2[ct * 16 + lr];

#pragma unroll
    for (int rt = 0; rt < 2; ++rt) {
        int lrow = w * 32 + rt * 16 + lr;
        f32x4 acc[4];
#pragma unroll
        for (int ct = 0; ct < 4; ++ct) acc[ct] = (f32x4){0.f, 0.f, 0.f, 0.f};
#pragma unroll
        for (int kc = 0; kc < 4; ++kc) {
            bf16x8 a = *reinterpret_cast<const bf16x8*>(&hl[lrow][kc * 32 + lg * 8]);
#pragma unroll
            for (int ct = 0; ct < 4; ++ct)
                acc[ct] = __builtin_amdgcn_mfma_f32_16x16x32_bf16(a, b2f[ct][kc], acc[ct], 0, 0, 0);
        }
        int orow = row0 + rt * 16 + lg * 4;
#pragma unroll
        for (int ct = 0; ct < 4; ++ct) {
#pragma unroll
            for (int r = 0; r < 4; ++r) {
                int row = orow + r;
                if (row < n) {
                    float g = acc[ct][r];
                    size_t o = (size_t)row * 64 + ct * 16 + lr;
                    out[o] = g + bias2[ct];
                    gh[o] = f2b(g);
                }
            }
        }
    }
}

extern "C" void kernel_launch(void* const* d_in, const int* in_sizes, int n_in,
                              void* d_out, int out_size, void* d_ws, size_t ws_size,
                              hipStream_t stream) {
    const float* node_emb = (const float*)d_in[0];
    const float* W1 = (const float*)d_in[1];
    const float* b1 = (const float*)d_in[2];
    const float* W2 = (const float*)d_in[3];
    const float* b2 = (const float*)d_in[4];
    const int*   ei = (const int*)d_in[5];
    int n  = in_sizes[0] / 64;
    int ne = in_sizes[5] / 2;
    const int* src = ei;
    const int* dst = ei + ne;
    float* out = (float*)d_out;

    int nbins = (n + 255) >> 8;   // 391

    // workspace layout (no aliasing needed; ~56 MB total, well under prior use)
    char* ws = (char*)d_ws;
    const size_t MB = 1024 * 1024;
    uint2*          agg1h = (uint2*)ws;                          // n*64 bf16 (12.8 MB)
    uint2*          gh    = (uint2*)(ws + 13 * MB);              // n*64 bf16 (12.8 MB)
    uint2*          xh    = (uint2*)(ws + 26 * MB);              // n*64 bf16 (12.8 MB)
    unsigned*       part  = (unsigned*)(ws + 39 * MB);           // ne u32 (6.4 MB)
    unsigned short* w1t   = (unsigned short*)(ws + 46 * MB);     // 16 KB
    unsigned short* w2t   = (unsigned short*)(ws + 46 * MB + 65536);
    int* off    = (int*)(ws + 47 * MB);                          // (n+1)*4
    int* perm   = (int*)(ws + 48 * MB);                          // ne*4 (6.4 MB)
    int* binCnt = (int*)(ws + 55 * MB);
    int* binOff = (int*)(ws + 55 * MB + 4096);
    int* binCur = (int*)(ws + 55 * MB + 8192);

    int nblk = (ne + EPB - 1) / EPB;

    cvt_bf16<<<(n * 16 + 255) / 256, 256, 0, stream>>>((const float4*)node_emb, xh, n * 16);
    prep_w1t<<<32, 256, 0, stream>>>(W1, w1t);
    prep_w2t<<<32, 256, 0, stream>>>(W2, w2t);
    hipMemsetAsync(binCnt, 0, (size_t)nbins * 4, stream);
    bin_hist<<<nblk, 256, 0, stream>>>(dst, binCnt, ne, nbins);
    scan_bins<<<1, 512, 0, stream>>>(binCnt, binOff, binCur, off, nbins, n, ne);
    partition<<<nblk, 256, 0, stream>>>(src, dst, binCur, part, ne, nbins);
    bin_finalize<<<nbins, 256, 0, stream>>>(part, binOff, off, perm, n, nbins);

    gather64h_b16<<<(n + 15) / 16, 256, 0, stream>>>(xh, (const float4*)node_emb, off, perm,
                                                     agg1h, n);
    mlp_fused<<<(n + 127) / 128, 256, 0, stream>>>((const unsigned short*)agg1h, w1t, b1,
                                                   w2t, b2, (unsigned short*)gh, out, n);
    gather64h<<<(n + 15) / 16, 256, 0, stream>>>(gh, (const float4*)out, off, perm,
                                                 (float4*)out, n);
}